// Round 11
// baseline (122.289 us; speedup 1.0000x reference)
//
#include <hip/hip_runtime.h>
#include <hip/hip_bf16.h>

// SparseAttentionHead on MI355X — v11: v4's proven k2 structure, but the adj
// HBM stream is moved OUT of the MFMA loop. New k0 streams adj (256MB f32)
// once at copy-ceiling BW and compresses it to a 1-bit mask (8MB, L2/L1-
// resident). k2's per-step VMEM is then all cache-resident (FT via
// global_load_lds from L2, mask byte from L1, a2 from L2) -> the per-step
// barrier drain waits ~300cy instead of ~900cy HBM latency.
// out[i,c] = elu( sum_j P[i,j]*F[j,c] / Z[i] ),
//   P[i,j] = bit(i,j) ? exp(lrelu(a1[i]+a2[j])) : 1.0 ,  Z[i] = sum_j P[i,j].

typedef short bf16x8 __attribute__((ext_vector_type(8)));
typedef float f32x4 __attribute__((ext_vector_type(4)));

static __device__ __forceinline__ short f2bf(float f) {
  union { float f; unsigned u; } v; v.f = f;
  unsigned r = v.u + 0x7fffu + ((v.u >> 16) & 1u);
  return (short)(r >> 16);
}

static __device__ __forceinline__ void gld16(const short* g, short* l) {
  __builtin_amdgcn_global_load_lds(
      (const __attribute__((address_space(1))) void*)g,
      (__attribute__((address_space(3))) void*)l, 16, 0, 0);
}

// K0: adj (64M f32) -> bitmask (8MB). Pure streaming, fully coalesced.
// Also zeroes a1/a2 (blocks 0..15) so k1's atomics start from 0.
__global__ __launch_bounds__(256) void k0_mask(
    const float* __restrict__ adj, unsigned char* __restrict__ mask,
    float* __restrict__ a1z) {
  const unsigned tid = blockIdx.x * 256 + threadIdx.x;
  if (blockIdx.x < 16) ((f32x4*)a1z)[tid] = f32x4{0.f, 0.f, 0.f, 0.f};
#pragma unroll 2
  for (int it = 0; it < 16; ++it) {
    const size_t b = (size_t)tid + (size_t)it * (2048u * 256u);  // byte index
    const f32x4 v0 = *(const f32x4*)(adj + b * 8);
    const f32x4 v1 = *(const f32x4*)(adj + b * 8 + 4);
    unsigned m = 0;
    m |= (v0[0] != 0.f) ? 1u : 0u;
    m |= (v0[1] != 0.f) ? 2u : 0u;
    m |= (v0[2] != 0.f) ? 4u : 0u;
    m |= (v0[3] != 0.f) ? 8u : 0u;
    m |= (v1[0] != 0.f) ? 16u : 0u;
    m |= (v1[1] != 0.f) ? 32u : 0u;
    m |= (v1[2] != 0.f) ? 64u : 0u;
    m |= (v1[3] != 0.f) ? 128u : 0u;
    mask[b] = (unsigned char)m;
  }
}

// K1: seq_fts = W1 @ x (fp32), store FT[c][n] = bf16, accumulate a1/a2.
__global__ __launch_bounds__(256) void k1_seqfts(
    const float* __restrict__ x, const float* __restrict__ W1,
    const float* __restrict__ wf1, const float* __restrict__ wf2,
    short* __restrict__ FT, float* __restrict__ a1, float* __restrict__ a2) {
  const int cb = blockIdx.x & 7;
  const int nb = blockIdx.x >> 3;
  const int n = nb * 256 + threadIdx.x;
  float acc[16];
#pragma unroll
  for (int i = 0; i < 16; ++i) acc[i] = 0.f;
  const float* wrow = W1 + cb * 16 * 128;
#pragma unroll 4
  for (int c = 0; c < 128; ++c) {
    float xv = x[c * 8192 + n];
#pragma unroll
    for (int cc = 0; cc < 16; ++cc) acc[cc] = fmaf(wrow[cc * 128 + c], xv, acc[cc]);
  }
  float p1 = 0.f, p2 = 0.f;
#pragma unroll
  for (int cc = 0; cc < 16; ++cc) {
    int co = cb * 16 + cc;
    FT[co * 8192 + n] = f2bf(acc[cc]);
    p1 = fmaf(wf1[co], acc[cc], p1);
    p2 = fmaf(wf2[co], acc[cc], p2);
  }
  atomicAdd(&a1[n], p1);
  atomicAdd(&a2[n], p2);
}

// K2: BM=32, BK=128, grid 256 (1 block/CU), 512 thr (8 waves). v4 structure.
__global__ __launch_bounds__(512, 2) void k2_attn(
    const unsigned char* __restrict__ mask, const short* __restrict__ FT,
    const float* __restrict__ a1, const float* __restrict__ a2,
    const float* __restrict__ b1p, const float* __restrict__ b2p,
    float* __restrict__ out) {
  __shared__ __align__(16) short Pl[2][4360];    // P dbuf, row stride 136
  __shared__ __align__(16) short Ftl[2][16384];  // FT dbuf, swizzled storage
  __shared__ float zl[32];

  const int t = threadIdx.x;
  const int l = t & 63;
  const int w = t >> 6;
  const int r = l & 15;
  const int kg = l >> 4;
  const int i0 = blockIdx.x * 32;

  // P producer: thread t -> row t>>4, k-cols (t&15)*8 .. +8
  const int prow = t >> 4;
  const int pcg = t & 15;
  const float af = a1[i0 + prow] + b1p[0] + b2p[0];
  const unsigned char* maskp = mask + (size_t)(i0 + prow) * 1024 + pcg;
  const float* a2p = a2 + pcg * 8;

  // FT staging (v4-verified): instr i covers c = i*32 + w*4 + kg; lane r = 16B
  // k-chunk; global source pre-swizzled +8*(r ^ (c&15)); LDS dest linear.
  const int swz = 8 * (r ^ ((w * 4 + kg) & 15));
  const short* fsrc0 = FT + (size_t)(0 + w * 4 + kg) * 8192 + swz;
  const short* fsrc1 = FT + (size_t)(32 + w * 4 + kg) * 8192 + swz;
  const short* fsrc2 = FT + (size_t)(64 + w * 4 + kg) * 8192 + swz;
  const short* fsrc3 = FT + (size_t)(96 + w * 4 + kg) * 8192 + swz;

  // MFMA mapping: wave w -> mtile w>>2 (16 rows), ntiles (w&3)*2 and +1.
  const int mt = w >> 2;
  const int ct0 = (w & 3) * 2;
  const int arow = mt * 16 + r;
  const int c0 = ct0 * 16 + r;

  f32x4 acc0 = {0.f, 0.f, 0.f, 0.f};
  f32x4 acc1 = {0.f, 0.f, 0.f, 0.f};
  float zacc = 0.f;

  auto build = [&](int buf, unsigned m, const f32x4& Q0, const f32x4& Q1) {
    bf16x8 pv;
#pragma unroll
    for (int j = 0; j < 4; ++j) {
      float tt = af + Q0[j];
      float lr = fmaxf(tt, 0.01f * tt);
      float ex = __expf(lr);
      float p = ((m >> j) & 1u) ? ex : 1.0f;
      zacc += p;
      pv[j] = f2bf(p);
    }
#pragma unroll
    for (int j = 0; j < 4; ++j) {
      float tt = af + Q1[j];
      float lr = fmaxf(tt, 0.01f * tt);
      float ex = __expf(lr);
      float p = ((m >> (4 + j)) & 1u) ? ex : 1.0f;
      zacc += p;
      pv[4 + j] = f2bf(p);
    }
    *(bf16x8*)&Pl[buf][prow * 136 + pcg * 8] = pv;
  };

  auto compute = [&](int cur) {
    const short* pb = &Pl[cur][arow * 136 + kg * 8];
    const short* fb = &Ftl[cur][0];
#pragma unroll
    for (int kt = 0; kt < 4; ++kt) {
      const int koff = (kg * 8 + kt * 32) ^ (r * 8);
      bf16x8 Af = *(const bf16x8*)(pb + kt * 32);
      bf16x8 B0 = *(const bf16x8*)(fb + c0 * 128 + koff);
      bf16x8 B1 = *(const bf16x8*)(fb + (c0 + 16) * 128 + koff);
      acc0 = __builtin_amdgcn_mfma_f32_16x16x32_bf16(Af, B0, acc0, 0, 0, 0);
      acc1 = __builtin_amdgcn_mfma_f32_16x16x32_bf16(Af, B1, acc1, 0, 0, 0);
    }
  };

  auto body = [&](int s, unsigned uM, const f32x4& uQ0, const f32x4& uQ1,
                  unsigned& fM, f32x4& fQ0, f32x4& fQ1) {
    const int cur = s & 1, nxt = cur ^ 1;
    if (s + 1 < 64) {                       // stage FT(s+1) -> Ftl[nxt]
      const int kb1 = (s + 1) * 128;
      short* fb = &Ftl[nxt][w * 512];
      gld16(fsrc0 + kb1, fb);
      gld16(fsrc1 + kb1, fb + 4096);
      gld16(fsrc2 + kb1, fb + 8192);
      gld16(fsrc3 + kb1, fb + 12288);
    }
    if (s + 2 < 64) {                       // mask/a2(s+2) -> refill regs
      fM = maskp[(s + 2) * 16];
      fQ0 = *(const f32x4*)(a2p + (s + 2) * 128);
      fQ1 = *(const f32x4*)(a2p + (s + 2) * 128 + 4);
    }
    if (s + 1 < 64) build(nxt, uM, uQ0, uQ1);  // P(s+1) from regs(s-1)
    compute(cur);                           // MFMA step s from LDS
    __syncthreads();                        // drain + swap (all L2-latency now)
  };

  // ---- prologue: FT(0) gloads; mask/a2(0)->tmp, (1)->O; build P(0) ----
  {
    short* fb = &Ftl[0][w * 512];
    gld16(fsrc0, fb);
    gld16(fsrc1, fb + 4096);
    gld16(fsrc2, fb + 8192);
    gld16(fsrc3, fb + 12288);
  }
  unsigned tM = maskp[0];
  f32x4 tQ0 = *(const f32x4*)(a2p);
  f32x4 tQ1 = *(const f32x4*)(a2p + 4);
  unsigned oM = maskp[16];
  f32x4 oQ0 = *(const f32x4*)(a2p + 128);
  f32x4 oQ1 = *(const f32x4*)(a2p + 132);
  unsigned eM = 0;
  f32x4 eQ0 = {0, 0, 0, 0}, eQ1 = {0, 0, 0, 0};
  build(0, tM, tQ0, tQ1);                   // P(0)
  __syncthreads();                          // P(0)+FT(0) visible, vmcnt drained

  for (int s = 0; s < 64; s += 2) {
    body(s, oM, oQ0, oQ1, eM, eQ0, eQ1);    // consume (s+1)=O, fetch (s+2)=E
    body(s + 1, eM, eQ0, eQ1, oM, oQ0, oQ1);// consume (s+2)=E, fetch (s+3)=O
  }

  // ---- Z: 16 threads per row -> zl[row] ----
  float zr = zacc;
  zr += __shfl_down(zr, 8, 16);
  zr += __shfl_down(zr, 4, 16);
  zr += __shfl_down(zr, 2, 16);
  zr += __shfl_down(zr, 1, 16);
  if (pcg == 0) zl[prow] = zr;
  __syncthreads();

  // ---- epilogue: C/D layout col=l&15, row=4*kg+q ----
#pragma unroll
  for (int q = 0; q < 4; ++q) {
    const int row = mt * 16 + kg * 4 + q;
    const float inv = 1.0f / zl[row];
    float v0 = acc0[q] * inv;
    v0 = v0 > 0.f ? v0 : __expf(v0) - 1.f;
    out[(size_t)(i0 + row) * 128 + c0] = v0;
    float v1 = acc1[q] * inv;
    v1 = v1 > 0.f ? v1 : __expf(v1) - 1.f;
    out[(size_t)(i0 + row) * 128 + c0 + 16] = v1;
  }
}

extern "C" void kernel_launch(void* const* d_in, const int* in_sizes, int n_in,
                              void* d_out, int out_size, void* d_ws, size_t ws_size,
                              hipStream_t stream) {
  const float* x   = (const float*)d_in[0];
  // d_in[1] = edge_index (unused by the reference computation)
  const float* adj = (const float*)d_in[2];
  const float* W1  = (const float*)d_in[3];
  const float* wf1 = (const float*)d_in[4];
  const float* b1  = (const float*)d_in[5];
  const float* wf2 = (const float*)d_in[6];
  const float* b2  = (const float*)d_in[7];
  float* out = (float*)d_out;

  short* FT = (short*)d_ws;                                     // 2 MB
  float* a1 = (float*)((char*)d_ws + (size_t)2 * 1024 * 1024);  // 8192 f32
  float* a2 = a1 + 8192;                                        // 8192 f32
  unsigned char* mask = (unsigned char*)d_ws + (size_t)4 * 1024 * 1024; // 8 MB

  k0_mask<<<2048, 256, 0, stream>>>(adj, mask, a1);  // also zeroes a1/a2
  k1_seqfts<<<256, 256, 0, stream>>>(x, W1, wf1, wf2, FT, a1, a2);
  k2_attn<<<256, 512, 0, stream>>>(mask, FT, a1, a2, b1, b2, out);
}

// Round 12
// 110.817 us; speedup vs baseline: 1.1035x; 1.1035x over previous
//
#include <hip/hip_runtime.h>
#include <hip/hip_bf16.h>

// SparseAttentionHead on MI355X — v13: BM=32, BK=256 (32 steps: halves the
// per-step fixed overhead count), FT dbuf 2x64KB via gload_lds with 5-bit
// XOR swizzle slot^=((c&15)<<1) (<=2-way on every access), P single 16KB
// buffer with the same swizzle, 2 barriers/step, adj prefetched 2 steps out
// in named E/O register bundles (fully coalesced 512B rows).
// out[i,c] = elu( sum_j P[i,j]*F[j,c] / Z[i] ),
//   P[i,j] = exp( adj[i,j]*lrelu(a1[i]+a2[j]) ), Z[i] = sum_j P[i,j].

typedef short bf16x8 __attribute__((ext_vector_type(8)));
typedef float f32x4 __attribute__((ext_vector_type(4)));

static __device__ __forceinline__ short f2bf(float f) {
  union { float f; unsigned u; } v; v.f = f;
  unsigned r = v.u + 0x7fffu + ((v.u >> 16) & 1u);
  return (short)(r >> 16);
}

static __device__ __forceinline__ void gld16(const short* g, short* l) {
  __builtin_amdgcn_global_load_lds(
      (const __attribute__((address_space(1))) void*)g,
      (__attribute__((address_space(3))) void*)l, 16, 0, 0);
}

// K1: seq_fts = W1 @ x (fp32), store FT[c][n] = bf16, accumulate a1/a2.
__global__ __launch_bounds__(256) void k1_seqfts(
    const float* __restrict__ x, const float* __restrict__ W1,
    const float* __restrict__ wf1, const float* __restrict__ wf2,
    short* __restrict__ FT, float* __restrict__ a1, float* __restrict__ a2) {
  const int cb = blockIdx.x & 7;
  const int nb = blockIdx.x >> 3;
  const int n = nb * 256 + threadIdx.x;
  float acc[16];
#pragma unroll
  for (int i = 0; i < 16; ++i) acc[i] = 0.f;
  const float* wrow = W1 + cb * 16 * 128;
#pragma unroll 4
  for (int c = 0; c < 128; ++c) {
    float xv = x[c * 8192 + n];
#pragma unroll
    for (int cc = 0; cc < 16; ++cc) acc[cc] = fmaf(wrow[cc * 128 + c], xv, acc[cc]);
  }
  float p1 = 0.f, p2 = 0.f;
#pragma unroll
  for (int cc = 0; cc < 16; ++cc) {
    int co = cb * 16 + cc;
    FT[co * 8192 + n] = f2bf(acc[cc]);
    p1 = fmaf(wf1[co], acc[cc], p1);
    p2 = fmaf(wf2[co], acc[cc], p2);
  }
  atomicAdd(&a1[n], p1);
  atomicAdd(&a2[n], p2);
}

// K2: BM=32, BK=256, grid 256 (1 block/CU), 512 thr (8 waves).
__global__ __launch_bounds__(512, 1) void k2_attn(
    const float* __restrict__ adj, const short* __restrict__ FT,
    const float* __restrict__ a1, const float* __restrict__ a2,
    const float* __restrict__ b1p, const float* __restrict__ b2p,
    float* __restrict__ out) {
  __shared__ __align__(16) short Ftl[2][32768];  // 128 c-rows x 256 k, swizzled
  __shared__ __align__(16) short Pl[8192];       // 32 rows x 256 k, swizzled
  __shared__ float zl[32];

  const int t = threadIdx.x;
  const int l = t & 63;
  const int w = t >> 6;
  const int r = l & 15;
  const int kg = l >> 4;
  const int i0 = blockIdx.x * 32;

  // P producer: thread t -> row t>>4, logical k slots pcg and pcg+16 (8 k each)
  const int prow = t >> 4;
  const int pcg = t & 15;
  const float af = a1[i0 + prow] + b1p[0] + b2p[0];
  const float* adjp = adj + (size_t)(i0 + prow) * 8192 + pcg * 8;
  const float* a2p = a2 + pcg * 8;
  const int psw = (prow & 15) << 1;                  // P swizzle term
  const int pw0 = prow * 256 + ((pcg ^ psw) << 3);
  const int pw1 = prow * 256 + (((pcg + 16) ^ psw) << 3);

  // FT staging: instr i covers c = i*16 + w*2 + (l>>5); lane = one 16B k-slot.
  // LDS dest linear; global source pre-swizzled by slot^((c&15)<<1).
  const int chalf = l >> 5;
  const int kslot = l & 31;

  // MFMA mapping: wave w -> mtile w>>2 (16 rows), ntiles (w&3)*2 and +1.
  const int mt = w >> 2;
  const int ct0 = (w & 3) * 2;
  const int arow = mt * 16 + r;
  const int c0 = ct0 * 16 + r;

  f32x4 acc0 = {0.f, 0.f, 0.f, 0.f};
  f32x4 acc1 = {0.f, 0.f, 0.f, 0.f};
  float zacc = 0.f;

  auto STAGE = [&](int s) {                 // 8 gload_lds per wave (64KB tile)
#pragma unroll
    for (int i = 0; i < 8; ++i) {
      const int c = i * 16 + w * 2 + chalf;
      const short* src = FT + (size_t)c * 8192 + s * 256 +
                         ((kslot ^ ((c & 15) << 1)) << 3);
      short* dst = &Ftl[s & 1][(i * 16 + w * 2) * 256];
      gld16(src, dst);
    }
  };

  auto build = [&](const f32x4& A0, const f32x4& A1, const f32x4& B0,
                   const f32x4& B1, const f32x4& Q0, const f32x4& Q1,
                   const f32x4& R0, const f32x4& R1) {
    bf16x8 pv0, pv1;
#pragma unroll
    for (int j = 0; j < 4; ++j) {
      float tt = af + Q0[j];
      float lr = fmaxf(tt, 0.01f * tt);
      float p = __expf(A0[j] * lr);
      zacc += p;
      pv0[j] = f2bf(p);
    }
#pragma unroll
    for (int j = 0; j < 4; ++j) {
      float tt = af + Q1[j];
      float lr = fmaxf(tt, 0.01f * tt);
      float p = __expf(A1[j] * lr);
      zacc += p;
      pv0[4 + j] = f2bf(p);
    }
#pragma unroll
    for (int j = 0; j < 4; ++j) {
      float tt = af + R0[j];
      float lr = fmaxf(tt, 0.01f * tt);
      float p = __expf(B0[j] * lr);
      zacc += p;
      pv1[j] = f2bf(p);
    }
#pragma unroll
    for (int j = 0; j < 4; ++j) {
      float tt = af + R1[j];
      float lr = fmaxf(tt, 0.01f * tt);
      float p = __expf(B1[j] * lr);
      zacc += p;
      pv1[4 + j] = f2bf(p);
    }
    *(bf16x8*)&Pl[pw0] = pv0;
    *(bf16x8*)&Pl[pw1] = pv1;
  };

  auto compute = [&](int s) {
    const short* pb = Pl + arow * 256;
    const short* fb = &Ftl[s & 1][0];
#pragma unroll
    for (int kt = 0; kt < 8; ++kt) {
      const int sl = (((kt * 4 + kg) ^ (r << 1)) << 3);   // shorts offset
      bf16x8 Af = *(const bf16x8*)(pb + sl);
      bf16x8 B0 = *(const bf16x8*)(fb + c0 * 256 + sl);
      bf16x8 B1 = *(const bf16x8*)(fb + (c0 + 16) * 256 + sl);
      acc0 = __builtin_amdgcn_mfma_f32_16x16x32_bf16(Af, B0, acc0, 0, 0, 0);
      acc1 = __builtin_amdgcn_mfma_f32_16x16x32_bf16(Af, B1, acc1, 0, 0, 0);
    }
  };

  // body(s): STAGE(s+1) [flies under compute]; refill regs <- adj(s+2);
  // compute(s); barrier A (P consumed); build P(s+1); lgkm0 + vmcnt(8)
  // [leaves only the 8 refill loads in flight]; barrier B (publish).
  auto body = [&](int s, const f32x4& uA0, const f32x4& uA1, const f32x4& uB0,
                  const f32x4& uB1, const f32x4& uQ0, const f32x4& uQ1,
                  const f32x4& uR0, const f32x4& uR1, f32x4& fA0, f32x4& fA1,
                  f32x4& fB0, f32x4& fB1, f32x4& fQ0, f32x4& fQ1, f32x4& fR0,
                  f32x4& fR1) {
    if (s + 1 < 32) STAGE(s + 1);
    __builtin_amdgcn_sched_barrier(0);      // STAGE stays older than refill
    if (s + 2 < 32) {
      const float* ap = adjp + (s + 2) * 256;
      fA0 = *(const f32x4*)(ap);
      fA1 = *(const f32x4*)(ap + 4);
      fB0 = *(const f32x4*)(ap + 128);
      fB1 = *(const f32x4*)(ap + 132);
      const float* qp = a2p + (s + 2) * 256;
      fQ0 = *(const f32x4*)(qp);
      fQ1 = *(const f32x4*)(qp + 4);
      fR0 = *(const f32x4*)(qp + 128);
      fR1 = *(const f32x4*)(qp + 132);
    }
    compute(s);
    __builtin_amdgcn_s_barrier();           // A: P(s)+Ftl[s&1] reads done
    if (s + 1 < 32) build(uA0, uA1, uB0, uB1, uQ0, uQ1, uR0, uR1);
    asm volatile("s_waitcnt lgkmcnt(0)" ::: "memory");
    asm volatile("s_waitcnt vmcnt(8)" ::: "memory");
    __builtin_amdgcn_s_barrier();           // B: P(s+1)+Ftl[(s+1)&1] visible
  };

  // ---- prologue ----
  STAGE(0);
  __builtin_amdgcn_sched_barrier(0);
  f32x4 eA0 = *(const f32x4*)(adjp);        // E <- adj(0)
  f32x4 eA1 = *(const f32x4*)(adjp + 4);
  f32x4 eB0 = *(const f32x4*)(adjp + 128);
  f32x4 eB1 = *(const f32x4*)(adjp + 132);
  f32x4 eQ0 = *(const f32x4*)(a2p);
  f32x4 eQ1 = *(const f32x4*)(a2p + 4);
  f32x4 eR0 = *(const f32x4*)(a2p + 128);
  f32x4 eR1 = *(const f32x4*)(a2p + 132);
  f32x4 oA0 = *(const f32x4*)(adjp + 256);  // O <- adj(1)
  f32x4 oA1 = *(const f32x4*)(adjp + 260);
  f32x4 oB0 = *(const f32x4*)(adjp + 384);
  f32x4 oB1 = *(const f32x4*)(adjp + 388);
  f32x4 oQ0 = *(const f32x4*)(a2p + 256);
  f32x4 oQ1 = *(const f32x4*)(a2p + 260);
  f32x4 oR0 = *(const f32x4*)(a2p + 384);
  f32x4 oR1 = *(const f32x4*)(a2p + 388);
  build(eA0, eA1, eB0, eB1, eQ0, eQ1, eR0, eR1);   // P(0)
  asm volatile("s_waitcnt lgkmcnt(0)" ::: "memory");
  asm volatile("s_waitcnt vmcnt(8)" ::: "memory");  // STAGE(0)+E done; O flies
  __builtin_amdgcn_s_barrier();             // P(0)+Ftl[0] visible

  for (int s = 0; s < 32; s += 2) {
    body(s, oA0, oA1, oB0, oB1, oQ0, oQ1, oR0, oR1,
         eA0, eA1, eB0, eB1, eQ0, eQ1, eR0, eR1);   // use adj(s+1)=O
    body(s + 1, eA0, eA1, eB0, eB1, eQ0, eQ1, eR0, eR1,
         oA0, oA1, oB0, oB1, oQ0, oQ1, oR0, oR1);   // use adj(s+2)=E
  }

  // ---- Z: 16 threads per row ----
  float zr = zacc;
  zr += __shfl_down(zr, 8, 16);
  zr += __shfl_down(zr, 4, 16);
  zr += __shfl_down(zr, 2, 16);
  zr += __shfl_down(zr, 1, 16);
  if (pcg == 0) zl[prow] = zr;
  __syncthreads();

  // ---- epilogue: C/D layout col=l&15, row=4*kg+q ----
#pragma unroll
  for (int q = 0; q < 4; ++q) {
    const int row = mt * 16 + kg * 4 + q;
    const float inv = 1.0f / zl[row];
    float v0 = acc0[q] * inv;
    v0 = v0 > 0.f ? v0 : __expf(v0) - 1.f;
    out[(size_t)(i0 + row) * 128 + c0] = v0;
    float v1 = acc1[q] * inv;
    v1 = v1 > 0.f ? v1 : __expf(v1) - 1.f;
    out[(size_t)(i0 + row) * 128 + c0 + 16] = v1;
  }
}

extern "C" void kernel_launch(void* const* d_in, const int* in_sizes, int n_in,
                              void* d_out, int out_size, void* d_ws, size_t ws_size,
                              hipStream_t stream) {
  const float* x   = (const float*)d_in[0];
  // d_in[1] = edge_index (unused by the reference computation)
  const float* adj = (const float*)d_in[2];
  const float* W1  = (const float*)d_in[3];
  const float* wf1 = (const float*)d_in[4];
  const float* b1  = (const float*)d_in[5];
  const float* wf2 = (const float*)d_in[6];
  const float* b2  = (const float*)d_in[7];
  float* out = (float*)d_out;

  short* FT = (short*)d_ws;                                    // 2 MB
  float* a1 = (float*)((char*)d_ws + (size_t)2 * 1024 * 1024); // 8192 f32
  float* a2 = a1 + 8192;                                       // 8192 f32

  hipMemsetAsync(a1, 0, 2 * 8192 * sizeof(float), stream);
  k1_seqfts<<<256, 256, 0, stream>>>(x, W1, wf1, wf2, FT, a1, a2);
  k2_attn<<<256, 512, 0, stream>>>(adj, FT, a1, a2, b1, b2, out);
}